// Round 1
// 185.909 us; speedup vs baseline: 1.0144x; 1.0144x over previous
//
#include <hip/hip_runtime.h>

// MultiHeadSelfAttention: B=2, S=2048, E=1024, H=16, D=64
// bf16 MFMA pipeline. R9: attn with paired q-tiles, kv-half split across the
// two 4-wave groups (exp2-softmax is associative: no running max -> O and l
// partials merge by addition). Every wave holds Q-fragments of BOTH tiles and
// computes its kv-half for each active tile, sharing K/V LDS fragment reads.
// Final wave-pair merge through an LDS overlay of the dead K/V buffers.
// Every wave in every block does exactly 264 MFMAs (perfect balance).

typedef unsigned short u16;
typedef short bf16x8 __attribute__((ext_vector_type(8)));
typedef float f32x4 __attribute__((ext_vector_type(4)));
typedef unsigned short u16x4 __attribute__((ext_vector_type(4)));

#define S_LEN 2048
#define EMB 1024
#define NH 16
#define HD 64
#define QKV_W 3072
#define BATCH 2
#define CSC 0.18033688f  // 0.125 * log2(e)
#define PSTR 72          // plds row stride (32 B-cols + 32 A-cols + pad)

static __device__ __forceinline__ u16 f2bf(float f) {
    unsigned x = __float_as_uint(f);
    return (u16)((x + 0x7fffu + ((x >> 16) & 1u)) >> 16);
}

static __device__ __forceinline__ void gld_lds16(const u16* g, u16* l) {
    __builtin_amdgcn_global_load_lds(
        (const __attribute__((address_space(1))) void*)g,
        (__attribute__((address_space(3))) void*)l, 16, 0, 0);
}

// ---------------- fused fp32 -> bf16 casts (3 ranges) ----------------
#define XN4 (BATCH * S_LEN * EMB / 4)      // 1048576
#define WQ4 (QKV_W * EMB / 4)              // 786432
#define W04 (EMB * EMB / 4)                // 262144
__global__ __launch_bounds__(256) void cvt_all(const float* __restrict__ x,
                                               const float* __restrict__ wq,
                                               const float* __restrict__ w0,
                                               u16* __restrict__ xb,
                                               u16* __restrict__ wqb,
                                               u16* __restrict__ w0b) {
    int i = blockIdx.x * 256 + threadIdx.x;
    const float* src;
    u16* dst;
    int off;
    if (i < XN4) { src = x; dst = xb; off = i; }
    else if (i < XN4 + WQ4) { src = wq; dst = wqb; off = i - XN4; }
    else { src = w0; dst = w0b; off = i - XN4 - WQ4; }
    float4 v = ((const float4*)src)[off];
    u16x4 o;
    o[0] = f2bf(v.x); o[1] = f2bf(v.y); o[2] = f2bf(v.z); o[3] = f2bf(v.w);
    ((u16x4*)dst)[off] = o;
}

// ---------------- GEMM: C[M,N] = A[M,K] @ Bt[N,K]^T ----------------
// BM=128, BN template (128 or 64), BK=32, 256 thr / 4 waves.
// Columns n < qcols scaled by CSC (Q pre-scaling for attention).
template <typename OutT, int BN>
__global__ __launch_bounds__(256) void gemm_bt(const u16* __restrict__ A,
                                               const u16* __restrict__ Bt,
                                               OutT* __restrict__ C,
                                               int M, int N, int K, int qcols) {
    constexpr int NF = BN / 32;  // n-frags per wave
    __shared__ alignas(16) u16 As[128 * 32];
    __shared__ alignas(16) u16 Bs[BN * 32];
    const int tid = threadIdx.x;
    const int wave = tid >> 6, lane = tid & 63;
    const int quad = lane >> 4, lr = lane & 15;
    const int m0 = blockIdx.y * 128, n0 = blockIdx.x * BN;
    const int wm = (wave & 1) * 64, wn = (wave >> 1) * (BN / 2);
    const float sc = (n0 < qcols) ? CSC : 1.0f;

    f32x4 acc[4][NF] = {};

    for (int k0 = 0; k0 < K; k0 += 32) {
#pragma unroll
        for (int i = 0; i < 2; ++i) {
            int chunk = tid + i * 256;
            int row = chunk >> 2;
            int col8 = (chunk & 3) * 8;
            gld_lds16(&A[(size_t)(m0 + row) * K + k0 + col8], &As[row * 32 + col8]);
        }
#pragma unroll
        for (int i = 0; i < BN / 64; ++i) {
            int chunk = tid + i * 256;
            int row = chunk >> 2;
            int col8 = (chunk & 3) * 8;
            gld_lds16(&Bt[(size_t)(n0 + row) * K + k0 + col8], &Bs[row * 32 + col8]);
        }
        __syncthreads();
        bf16x8 af[4], bf[NF];
#pragma unroll
        for (int i = 0; i < 4; ++i)
            af[i] = *(const bf16x8*)&As[(wm + i * 16 + lr) * 32 + quad * 8];
#pragma unroll
        for (int i = 0; i < NF; ++i)
            bf[i] = *(const bf16x8*)&Bs[(wn + i * 16 + lr) * 32 + quad * 8];
#pragma unroll
        for (int mi = 0; mi < 4; ++mi)
#pragma unroll
            for (int ni = 0; ni < NF; ++ni)
                acc[mi][ni] = __builtin_amdgcn_mfma_f32_16x16x32_bf16(
                    af[mi], bf[ni], acc[mi][ni], 0, 0, 0);
        __syncthreads();
    }

#pragma unroll
    for (int mi = 0; mi < 4; ++mi) {
#pragma unroll
        for (int r = 0; r < 4; ++r) {
            int gr = m0 + wm + mi * 16 + quad * 4 + r;
#pragma unroll
            for (int ni = 0; ni < NF; ++ni) {
                int gc = n0 + wn + ni * 16 + lr;
                float v = acc[mi][ni][r] * sc;
                if constexpr (sizeof(OutT) == 2)
                    C[(size_t)gr * N + gc] = (OutT)f2bf(v);
                else
                    C[(size_t)gr * N + gc] = (OutT)v;
            }
        }
    }
}

// ---------------- V transpose: qkv[.,2048+h*64+d] -> vt[bh][d][s] ----------------
__global__ __launch_bounds__(256) void transpose_v(const u16* __restrict__ qkv,
                                                   u16* __restrict__ vt) {
    __shared__ alignas(16) u16 t[64][72];
    const int s0 = blockIdx.x * 64;
    const int bh = blockIdx.y;
    const int b = bh >> 4, h = bh & 15;
#pragma unroll
    for (int i = 0; i < 2; ++i) {
        int chunk = threadIdx.x + i * 256;
        int row = chunk >> 3;
        int c8 = (chunk & 7) * 8;
        uint4 v = *(const uint4*)&qkv[(size_t)(b * S_LEN + s0 + row) * QKV_W +
                                      2 * EMB + h * HD + c8];
        const u16* p = (const u16*)&v;
#pragma unroll
        for (int jj = 0; jj < 8; ++jj) t[c8 + jj][row] = p[jj];
    }
    __syncthreads();
#pragma unroll
    for (int i = 0; i < 2; ++i) {
        int chunk = threadIdx.x + i * 256;
        int d = chunk >> 3;
        int c8 = (chunk & 7) * 8;
        uint4 v = *(const uint4*)&t[d][c8];
        *(uint4*)&vt[((size_t)bh * HD + d) * S_LEN + s0 + c8] = v;
    }
}

// ---------------- Flash attention (causal), R9 ----------------
// grid (16, 32), 512 thr = 8 waves. Block pi owns q-tiles tA=pi, tB=31-pi.
// Wave w: q-rows (w&3)*16 of BOTH tiles; kv-half hv=w>>2 (rows hv*32..+32)
// of every staged KV tile. Tile B computed every iter, tile A while j<=tA.
// K/V LDS fragment reads shared between the two tiles. Wave pairs (w, w+4)
// hold complementary kv-halves; (O, l) partials merged via LDS at the end
// (valid because p = exp2(s) with no running max -> fully associative).
__global__ __launch_bounds__(512, 4) void attn(const u16* __restrict__ qkv,
                                               const u16* __restrict__ vt,
                                               u16* __restrict__ e) {
    const int tid = threadIdx.x;
    const int w = tid >> 6, lane = tid & 63;
    const int quad = lane >> 4, lr = lane & 15;
    const int wq = w & 3, hv = w >> 2;
    const int tA = blockIdx.x;   // 0..15
    const int tB = 31 - tA;      // 16..31
    const int bh = blockIdx.y, b = bh >> 4, h = bh & 15;

    __shared__ alignas(16) u16 smem[25600];  // 51200 B
    u16* Ks = smem;           // 2 buf x [d-half][kv row 64][32] = 8192 u16
    u16* Vs = smem + 8192;    // 2 buf x [kv-half][d row 64][32] = 8192 u16
    u16* pw = smem + 16384 + w * 16 * PSTR;  // per-wave P scratch

    const u16* qkv_b = qkv + (size_t)b * S_LEN * QKV_W;
    const u16* qrowA = qkv_b + (size_t)(tA * 64 + wq * 16 + lr) * QKV_W + h * HD + quad * 8;
    const u16* qrowB = qkv_b + (size_t)(tB * 64 + wq * 16 + lr) * QKV_W + h * HD + quad * 8;
    const bf16x8 qfA0 = *(const bf16x8*)(qrowA);
    const bf16x8 qfA1 = *(const bf16x8*)(qrowA + 32);
    const bf16x8 qfB0 = *(const bf16x8*)(qrowB);
    const bf16x8 qfB1 = *(const bf16x8*)(qrowB + 32);

    const u16* kbase = qkv_b + EMB + h * HD;          // K[s][d], stride 3072
    const u16* vbase = vt + (size_t)bh * HD * S_LEN;  // V^T[d][s], stride 2048

    f32x4 oA[4] = {}, oB[4] = {};
    float lsA = 0.f, lsB = 0.f;
    const int qgA = tA * 64 + wq * 16 + lr;
    const int qgB = tB * 64 + wq * 16 + lr;

    // staging role: waves 0-3 -> K rows, waves 4-7 -> V rows
    const int sr = wq * 16 + (lane >> 2);  // row 0..63
    const int sc = (lane & 3) * 8;         // 0,8,16,24

    auto stage = [&](int j, int bb) {
        const int kv0 = j * 64;
        if (w < 4) {
            gld_lds16(kbase + (size_t)(kv0 + sr) * QKV_W + sc,
                      &Ks[bb * 4096 + sr * 32 + sc]);
            gld_lds16(kbase + (size_t)(kv0 + sr) * QKV_W + 32 + sc,
                      &Ks[bb * 4096 + 2048 + sr * 32 + sc]);
        } else {
            gld_lds16(vbase + (size_t)sr * S_LEN + kv0 + sc,
                      &Vs[bb * 4096 + sr * 32 + sc]);
            gld_lds16(vbase + (size_t)sr * S_LEN + kv0 + 32 + sc,
                      &Vs[bb * 4096 + 2048 + sr * 32 + sc]);
        }
    };

    stage(0, 0);
    for (int j = 0; j <= tB; ++j) {
        const int bb = j & 1;
        __syncthreads();  // staged buf bb complete; other buf free
        if (j < tB) stage(j + 1, 1 - bb);
        const bool doA = (j <= tA);
        const u16* ks = &Ks[bb * 4096];
        const u16* vs = &Vs[bb * 4096];
        const int kvh = hv * 32;  // this wave's kv-half within the tile

        // ---- S^T for both tiles, shared K fragments ----
        f32x4 sB[2], sA[2];
#pragma unroll
        for (int nt = 0; nt < 2; ++nt) {
            const int kvr = kvh + nt * 16 + lr;
            bf16x8 k0 = *(const bf16x8*)&ks[kvr * 32 + quad * 8];
            bf16x8 k1 = *(const bf16x8*)&ks[2048 + kvr * 32 + quad * 8];
            f32x4 z = {};
            z = __builtin_amdgcn_mfma_f32_16x16x32_bf16(k0, qfB0, z, 0, 0, 0);
            z = __builtin_amdgcn_mfma_f32_16x16x32_bf16(k1, qfB1, z, 0, 0, 0);
            sB[nt] = z;
            if (doA) {
                f32x4 za = {};
                za = __builtin_amdgcn_mfma_f32_16x16x32_bf16(k0, qfA0, za, 0, 0, 0);
                za = __builtin_amdgcn_mfma_f32_16x16x32_bf16(k1, qfA1, za, 0, 0, 0);
                sA[nt] = za;
            }
        }

        // ---- softmax: p = exp2(s); mask on the diagonal tile ----
        const int kvg = j * 64 + kvh;
        __builtin_amdgcn_wave_barrier();
#pragma unroll
        for (int nt = 0; nt < 2; ++nt) {
            float p[4];
#pragma unroll
            for (int r = 0; r < 4; ++r) {
                float pv = exp2f(sB[nt][r]);
                if (j == tB) pv = (kvg + nt * 16 + quad * 4 + r > qgB) ? 0.f : pv;
                p[r] = pv;
            }
            lsB += (p[0] + p[1]) + (p[2] + p[3]);
            uint2 pk;  // truncation pack: hi16 of each float
            pk.x = __builtin_amdgcn_perm(__float_as_uint(p[1]),
                                         __float_as_uint(p[0]), 0x07060302u);
            pk.y = __builtin_amdgcn_perm(__float_as_uint(p[3]),
                                         __float_as_uint(p[2]), 0x07060302u);
            *(uint2*)&pw[lr * PSTR + nt * 16 + quad * 4] = pk;
        }
        if (doA) {
#pragma unroll
            for (int nt = 0; nt < 2; ++nt) {
                float p[4];
#pragma unroll
                for (int r = 0; r < 4; ++r) {
                    float pv = exp2f(sA[nt][r]);
                    if (j == tA) pv = (kvg + nt * 16 + quad * 4 + r > qgA) ? 0.f : pv;
                    p[r] = pv;
                }
                lsA += (p[0] + p[1]) + (p[2] + p[3]);
                uint2 pk;
                pk.x = __builtin_amdgcn_perm(__float_as_uint(p[1]),
                                             __float_as_uint(p[0]), 0x07060302u);
                pk.y = __builtin_amdgcn_perm(__float_as_uint(p[3]),
                                             __float_as_uint(p[2]), 0x07060302u);
                *(uint2*)&pw[lr * PSTR + 32 + nt * 16 + quad * 4] = pk;
            }
        }
        __builtin_amdgcn_wave_barrier();
        const bf16x8 pB = *(const bf16x8*)&pw[lr * PSTR + quad * 8];
        bf16x8 pA = {};
        if (doA) pA = *(const bf16x8*)&pw[lr * PSTR + 32 + quad * 8];

        // ---- O += P @ V, shared V fragments ----
#pragma unroll
        for (int nt = 0; nt < 4; ++nt) {
            bf16x8 v = *(const bf16x8*)&vs[hv * 2048 + (nt * 16 + lr) * 32 + quad * 8];
            oB[nt] = __builtin_amdgcn_mfma_f32_16x16x32_bf16(pB, v, oB[nt], 0, 0, 0);
            if (doA) oA[nt] = __builtin_amdgcn_mfma_f32_16x16x32_bf16(pA, v, oA[nt], 0, 0, 0);
        }
    }

    // ---- merge wave-pair (kv-half) partials via LDS overlay, finalize ----
    float lfA = lsA + __shfl_xor(lsA, 16, 64);
    lfA += __shfl_xor(lfA, 32, 64);
    float lfB = lsB + __shfl_xor(lsB, 16, 64);
    lfB += __shfl_xor(lfB, 32, 64);
    __syncthreads();  // all compute done; K/V/P LDS dead -> reuse
    float* mA = (float*)smem;       // [64][66] f32 tile-A partials
    float* mB = mA + 64 * 66;       // [64][66] f32 tile-B partials
    float* lAr = mB + 64 * 66;      // [64] row sums (tile A, half 1)
    float* lBr = lAr + 64;          // [64] row sums (tile B, half 0)
    if (hv) {
#pragma unroll
        for (int nt = 0; nt < 4; ++nt)
#pragma unroll
            for (int r = 0; r < 4; ++r)
                mA[(wq * 16 + quad * 4 + r) * 66 + nt * 16 + lr] = oA[nt][r];
        if (lane < 16) lAr[wq * 16 + lane] = lfA;
    } else {
#pragma unroll
        for (int nt = 0; nt < 4; ++nt)
#pragma unroll
            for (int r = 0; r < 4; ++r)
                mB[(wq * 16 + quad * 4 + r) * 66 + nt * 16 + lr] = oB[nt][r];
        if (lane < 16) lBr[wq * 16 + lane] = lfB;
    }
    __syncthreads();
    if (!hv) {  // waves 0-3 finalize tile A
        float lff = lfA + lAr[wq * 16 + lr];
#pragma unroll
        for (int r = 0; r < 4; ++r) {
            float inv = 1.0f / __shfl(lff, quad * 4 + r, 64);
            size_t row = (size_t)(b * S_LEN + tA * 64 + wq * 16 + quad * 4 + r) * EMB + h * HD;
#pragma unroll
            for (int nt = 0; nt < 4; ++nt)
                e[row + nt * 16 + lr] =
                    f2bf((oA[nt][r] + mA[(wq * 16 + quad * 4 + r) * 66 + nt * 16 + lr]) * inv);
        }
    } else {  // waves 4-7 finalize tile B
        float lff = lfB + lBr[wq * 16 + lr];
#pragma unroll
        for (int r = 0; r < 4; ++r) {
            float inv = 1.0f / __shfl(lff, quad * 4 + r, 64);
            size_t row = (size_t)(b * S_LEN + tB * 64 + wq * 16 + quad * 4 + r) * EMB + h * HD;
#pragma unroll
            for (int nt = 0; nt < 4; ++nt)
                e[row + nt * 16 + lr] =
                    f2bf((oB[nt][r] + mB[(wq * 16 + quad * 4 + r) * 66 + nt * 16 + lr]) * inv);
        }
    }
}

// ---------------- launcher ----------------
extern "C" void kernel_launch(void* const* d_in, const int* in_sizes, int n_in,
                              void* d_out, int out_size, void* d_ws, size_t ws_size,
                              hipStream_t stream) {
    const float* x = (const float*)d_in[0];
    const float* w_qkv = (const float*)d_in[1];
    const float* w0 = (const float*)d_in[2];
    float* out = (float*)d_out;

    const size_t M = (size_t)BATCH * S_LEN;  // 4096
    u16* xb = (u16*)d_ws;
    u16* wqb = xb + M * EMB;
    u16* w0b = wqb + (size_t)QKV_W * EMB;
    u16* qkvb = w0b + (size_t)EMB * EMB;
    u16* vtb = qkvb + M * QKV_W;
    u16* eb = vtb + (size_t)BATCH * NH * HD * S_LEN;

    cvt_all<<<(XN4 + WQ4 + W04) / 256, 256, 0, stream>>>(x, w_qkv, w0, xb, wqb, w0b);

    // qkv = x @ w_qkv^T; Q columns pre-scaled by CSC
    gemm_bt<u16, 128><<<dim3(QKV_W / 128, M / 128), 256, 0, stream>>>(
        xb, wqb, qkvb, (int)M, QKV_W, EMB, EMB);

    transpose_v<<<dim3(S_LEN / 64, BATCH * NH), 256, 0, stream>>>(qkvb, vtb);

    attn<<<dim3(16, BATCH * NH), 512, 0, stream>>>(qkvb, vtb, eb);

    // out = e @ w0^T (128x64 tiles -> 512 blocks, 2/CU)
    gemm_bt<float, 64><<<dim3(EMB / 64, M / 128), 256, 0, stream>>>(
        eb, w0b, out, (int)M, EMB, EMB, 0);
}

// Round 2
// 183.275 us; speedup vs baseline: 1.0290x; 1.0144x over previous
//
#include <hip/hip_runtime.h>

// MultiHeadSelfAttention: B=2, S=2048, E=1024, H=16, D=64
// bf16 MFMA pipeline. R10: R9 (paired q-tiles, kv-half split, balanced waves)
// + XOR bank-swizzle on the K/V LDS tiles. The [row][64B] tiles had an 8-way
// bank conflict on ds_read_b128 fragment reads (16-lane group hits only 2
// bank-groups). Swizzle: 16B-chunk ^= (row>>1)&3, applied as pre-swizzled
// GLOBAL source (global_load_lds writes linearly) + swizzled read chunk.
// Bit-identical data; conflicts 8-way -> 2-way (free).

typedef unsigned short u16;
typedef short bf16x8 __attribute__((ext_vector_type(8)));
typedef float f32x4 __attribute__((ext_vector_type(4)));
typedef unsigned short u16x4 __attribute__((ext_vector_type(4)));

#define S_LEN 2048
#define EMB 1024
#define NH 16
#define HD 64
#define QKV_W 3072
#define BATCH 2
#define CSC 0.18033688f  // 0.125 * log2(e)
#define PSTR 72          // plds row stride (32 B-cols + 32 A-cols + pad)

static __device__ __forceinline__ u16 f2bf(float f) {
    unsigned x = __float_as_uint(f);
    return (u16)((x + 0x7fffu + ((x >> 16) & 1u)) >> 16);
}

static __device__ __forceinline__ void gld_lds16(const u16* g, u16* l) {
    __builtin_amdgcn_global_load_lds(
        (const __attribute__((address_space(1))) void*)g,
        (__attribute__((address_space(3))) void*)l, 16, 0, 0);
}

// ---------------- fused fp32 -> bf16 casts (3 ranges) ----------------
#define XN4 (BATCH * S_LEN * EMB / 4)      // 1048576
#define WQ4 (QKV_W * EMB / 4)              // 786432
#define W04 (EMB * EMB / 4)                // 262144
__global__ __launch_bounds__(256) void cvt_all(const float* __restrict__ x,
                                               const float* __restrict__ wq,
                                               const float* __restrict__ w0,
                                               u16* __restrict__ xb,
                                               u16* __restrict__ wqb,
                                               u16* __restrict__ w0b) {
    int i = blockIdx.x * 256 + threadIdx.x;
    const float* src;
    u16* dst;
    int off;
    if (i < XN4) { src = x; dst = xb; off = i; }
    else if (i < XN4 + WQ4) { src = wq; dst = wqb; off = i - XN4; }
    else { src = w0; dst = w0b; off = i - XN4 - WQ4; }
    float4 v = ((const float4*)src)[off];
    u16x4 o;
    o[0] = f2bf(v.x); o[1] = f2bf(v.y); o[2] = f2bf(v.z); o[3] = f2bf(v.w);
    ((u16x4*)dst)[off] = o;
}

// ---------------- GEMM: C[M,N] = A[M,K] @ Bt[N,K]^T ----------------
// BM=128, BN template (128 or 64), BK=32, 256 thr / 4 waves.
// Columns n < qcols scaled by CSC (Q pre-scaling for attention).
// (2-phase structure: LDS swizzle is measured-null here - regime gate.)
template <typename OutT, int BN>
__global__ __launch_bounds__(256) void gemm_bt(const u16* __restrict__ A,
                                               const u16* __restrict__ Bt,
                                               OutT* __restrict__ C,
                                               int M, int N, int K, int qcols) {
    constexpr int NF = BN / 32;  // n-frags per wave
    __shared__ alignas(16) u16 As[128 * 32];
    __shared__ alignas(16) u16 Bs[BN * 32];
    const int tid = threadIdx.x;
    const int wave = tid >> 6, lane = tid & 63;
    const int quad = lane >> 4, lr = lane & 15;
    const int m0 = blockIdx.y * 128, n0 = blockIdx.x * BN;
    const int wm = (wave & 1) * 64, wn = (wave >> 1) * (BN / 2);
    const float sc = (n0 < qcols) ? CSC : 1.0f;

    f32x4 acc[4][NF] = {};

    for (int k0 = 0; k0 < K; k0 += 32) {
#pragma unroll
        for (int i = 0; i < 2; ++i) {
            int chunk = tid + i * 256;
            int row = chunk >> 2;
            int col8 = (chunk & 3) * 8;
            gld_lds16(&A[(size_t)(m0 + row) * K + k0 + col8], &As[row * 32 + col8]);
        }
#pragma unroll
        for (int i = 0; i < BN / 64; ++i) {
            int chunk = tid + i * 256;
            int row = chunk >> 2;
            int col8 = (chunk & 3) * 8;
            gld_lds16(&Bt[(size_t)(n0 + row) * K + k0 + col8], &Bs[row * 32 + col8]);
        }
        __syncthreads();
        bf16x8 af[4], bf[NF];
#pragma unroll
        for (int i = 0; i < 4; ++i)
            af[i] = *(const bf16x8*)&As[(wm + i * 16 + lr) * 32 + quad * 8];
#pragma unroll
        for (int i = 0; i < NF; ++i)
            bf[i] = *(const bf16x8*)&Bs[(wn + i * 16 + lr) * 32 + quad * 8];
#pragma unroll
        for (int mi = 0; mi < 4; ++mi)
#pragma unroll
            for (int ni = 0; ni < NF; ++ni)
                acc[mi][ni] = __builtin_amdgcn_mfma_f32_16x16x32_bf16(
                    af[mi], bf[ni], acc[mi][ni], 0, 0, 0);
        __syncthreads();
    }

#pragma unroll
    for (int mi = 0; mi < 4; ++mi) {
#pragma unroll
        for (int r = 0; r < 4; ++r) {
            int gr = m0 + wm + mi * 16 + quad * 4 + r;
#pragma unroll
            for (int ni = 0; ni < NF; ++ni) {
                int gc = n0 + wn + ni * 16 + lr;
                float v = acc[mi][ni][r] * sc;
                if constexpr (sizeof(OutT) == 2)
                    C[(size_t)gr * N + gc] = (OutT)f2bf(v);
                else
                    C[(size_t)gr * N + gc] = (OutT)v;
            }
        }
    }
}

// ---------------- V transpose: qkv[.,2048+h*64+d] -> vt[bh][d][s] ----------------
__global__ __launch_bounds__(256) void transpose_v(const u16* __restrict__ qkv,
                                                   u16* __restrict__ vt) {
    __shared__ alignas(16) u16 t[64][72];
    const int s0 = blockIdx.x * 64;
    const int bh = blockIdx.y;
    const int b = bh >> 4, h = bh & 15;
#pragma unroll
    for (int i = 0; i < 2; ++i) {
        int chunk = threadIdx.x + i * 256;
        int row = chunk >> 3;
        int c8 = (chunk & 7) * 8;
        uint4 v = *(const uint4*)&qkv[(size_t)(b * S_LEN + s0 + row) * QKV_W +
                                      2 * EMB + h * HD + c8];
        const u16* p = (const u16*)&v;
#pragma unroll
        for (int jj = 0; jj < 8; ++jj) t[c8 + jj][row] = p[jj];
    }
    __syncthreads();
#pragma unroll
    for (int i = 0; i < 2; ++i) {
        int chunk = threadIdx.x + i * 256;
        int d = chunk >> 3;
        int c8 = (chunk & 7) * 8;
        uint4 v = *(const uint4*)&t[d][c8];
        *(uint4*)&vt[((size_t)bh * HD + d) * S_LEN + s0 + c8] = v;
    }
}

// ---------------- Flash attention (causal), R10 ----------------
// grid (16, 32), 512 thr = 8 waves. Block pi owns q-tiles tA=pi, tB=31-pi.
// Wave w: q-rows (w&3)*16 of BOTH tiles; kv-half hv=w>>2 of every staged KV
// tile. K/V LDS fragment reads shared between the two tiles; wave pairs
// (w, w+4) merge (O, l) partials via LDS at the end (exp2-softmax, no
// running max -> associative). K/V tiles XOR-bank-swizzled (see header).
__global__ __launch_bounds__(512, 4) void attn(const u16* __restrict__ qkv,
                                               const u16* __restrict__ vt,
                                               u16* __restrict__ e) {
    const int tid = threadIdx.x;
    const int w = tid >> 6, lane = tid & 63;
    const int quad = lane >> 4, lr = lane & 15;
    const int wq = w & 3, hv = w >> 2;
    const int tA = blockIdx.x;   // 0..15
    const int tB = 31 - tA;      // 16..31
    const int bh = blockIdx.y, b = bh >> 4, h = bh & 15;

    __shared__ alignas(16) u16 smem[25600];  // 51200 B
    u16* Ks = smem;           // 2 buf x [d-half][kv row 64][32] = 8192 u16
    u16* Vs = smem + 8192;    // 2 buf x [kv-half][d row 64][32] = 8192 u16
    u16* pw = smem + 16384 + w * 16 * PSTR;  // per-wave P scratch

    const u16* qkv_b = qkv + (size_t)b * S_LEN * QKV_W;
    const u16* qrowA = qkv_b + (size_t)(tA * 64 + wq * 16 + lr) * QKV_W + h * HD + quad * 8;
    const u16* qrowB = qkv_b + (size_t)(tB * 64 + wq * 16 + lr) * QKV_W + h * HD + quad * 8;
    const bf16x8 qfA0 = *(const bf16x8*)(qrowA);
    const bf16x8 qfA1 = *(const bf16x8*)(qrowA + 32);
    const bf16x8 qfB0 = *(const bf16x8*)(qrowB);
    const bf16x8 qfB1 = *(const bf16x8*)(qrowB + 32);

    const u16* kbase = qkv_b + EMB + h * HD;          // K[s][d], stride 3072
    const u16* vbase = vt + (size_t)bh * HD * S_LEN;  // V^T[d][s], stride 2048

    f32x4 oA[4] = {}, oB[4] = {};
    float lsA = 0.f, lsB = 0.f;
    const int qgA = tA * 64 + wq * 16 + lr;
    const int qgB = tB * 64 + wq * 16 + lr;

    // staging role: waves 0-3 -> K rows, waves 4-7 -> V rows.
    // LDS dest stays LINEAR in lane (gld_lds requirement); the bank-swizzle
    // is applied by permuting the GLOBAL source 16B chunk per destination row:
    // slot (row, c') receives global chunk c' ^ ((row>>1)&3).
    const int sr = wq * 16 + (lane >> 2);                    // dest row 0..63
    const int scl = (lane & 3) * 8;                          // dest chunk (linear)
    const int scg = ((lane & 3) ^ ((lane >> 3) & 3)) * 8;    // swizzled source chunk

    auto stage = [&](int j, int bb) {
        const int kv0 = j * 64;
        if (w < 4) {
            gld_lds16(kbase + (size_t)(kv0 + sr) * QKV_W + scg,
                      &Ks[bb * 4096 + sr * 32 + scl]);
            gld_lds16(kbase + (size_t)(kv0 + sr) * QKV_W + 32 + scg,
                      &Ks[bb * 4096 + 2048 + sr * 32 + scl]);
        } else {
            gld_lds16(vbase + (size_t)sr * S_LEN + kv0 + scg,
                      &Vs[bb * 4096 + sr * 32 + scl]);
            gld_lds16(vbase + (size_t)sr * S_LEN + kv0 + 32 + scg,
                      &Vs[bb * 4096 + 2048 + sr * 32 + scl]);
        }
    };

    // fragment-read chunk, swizzled: quad ^ ((row>>1)&3) with row ≡ lr mod 16
    const int xq8 = (quad ^ ((lr >> 1) & 3)) * 8;

    stage(0, 0);
    for (int j = 0; j <= tB; ++j) {
        const int bb = j & 1;
        __syncthreads();  // staged buf bb complete; other buf free
        if (j < tB) stage(j + 1, 1 - bb);
        const bool doA = (j <= tA);
        const u16* ks = &Ks[bb * 4096];
        const u16* vs = &Vs[bb * 4096];
        const int kvh = hv * 32;  // this wave's kv-half within the tile

        // ---- S^T for both tiles, shared K fragments ----
        f32x4 sB[2], sA[2];
#pragma unroll
        for (int nt = 0; nt < 2; ++nt) {
            const int kvr = kvh + nt * 16 + lr;
            bf16x8 k0 = *(const bf16x8*)&ks[kvr * 32 + xq8];
            bf16x8 k1 = *(const bf16x8*)&ks[2048 + kvr * 32 + xq8];
            f32x4 z = {};
            z = __builtin_amdgcn_mfma_f32_16x16x32_bf16(k0, qfB0, z, 0, 0, 0);
            z = __builtin_amdgcn_mfma_f32_16x16x32_bf16(k1, qfB1, z, 0, 0, 0);
            sB[nt] = z;
            if (doA) {
                f32x4 za = {};
                za = __builtin_amdgcn_mfma_f32_16x16x32_bf16(k0, qfA0, za, 0, 0, 0);
                za = __builtin_amdgcn_mfma_f32_16x16x32_bf16(k1, qfA1, za, 0, 0, 0);
                sA[nt] = za;
            }
        }

        // ---- softmax: p = exp2(s); mask on the diagonal tile ----
        const int kvg = j * 64 + kvh;
        __builtin_amdgcn_wave_barrier();
#pragma unroll
        for (int nt = 0; nt < 2; ++nt) {
            float p[4];
#pragma unroll
            for (int r = 0; r < 4; ++r) {
                float pv = exp2f(sB[nt][r]);
                if (j == tB) pv = (kvg + nt * 16 + quad * 4 + r > qgB) ? 0.f : pv;
                p[r] = pv;
            }
            lsB += (p[0] + p[1]) + (p[2] + p[3]);
            uint2 pk;  // truncation pack: hi16 of each float
            pk.x = __builtin_amdgcn_perm(__float_as_uint(p[1]),
                                         __float_as_uint(p[0]), 0x07060302u);
            pk.y = __builtin_amdgcn_perm(__float_as_uint(p[3]),
                                         __float_as_uint(p[2]), 0x07060302u);
            *(uint2*)&pw[lr * PSTR + nt * 16 + quad * 4] = pk;
        }
        if (doA) {
#pragma unroll
            for (int nt = 0; nt < 2; ++nt) {
                float p[4];
#pragma unroll
                for (int r = 0; r < 4; ++r) {
                    float pv = exp2f(sA[nt][r]);
                    if (j == tA) pv = (kvg + nt * 16 + quad * 4 + r > qgA) ? 0.f : pv;
                    p[r] = pv;
                }
                lsA += (p[0] + p[1]) + (p[2] + p[3]);
                uint2 pk;
                pk.x = __builtin_amdgcn_perm(__float_as_uint(p[1]),
                                             __float_as_uint(p[0]), 0x07060302u);
                pk.y = __builtin_amdgcn_perm(__float_as_uint(p[3]),
                                             __float_as_uint(p[2]), 0x07060302u);
                *(uint2*)&pw[lr * PSTR + 32 + nt * 16 + quad * 4] = pk;
            }
        }
        __builtin_amdgcn_wave_barrier();
        const bf16x8 pB = *(const bf16x8*)&pw[lr * PSTR + quad * 8];
        bf16x8 pA = {};
        if (doA) pA = *(const bf16x8*)&pw[lr * PSTR + 32 + quad * 8];

        // ---- O += P @ V, shared V fragments ----
#pragma unroll
        for (int nt = 0; nt < 4; ++nt) {
            bf16x8 v = *(const bf16x8*)&vs[hv * 2048 + (nt * 16 + lr) * 32 + xq8];
            oB[nt] = __builtin_amdgcn_mfma_f32_16x16x32_bf16(pB, v, oB[nt], 0, 0, 0);
            if (doA) oA[nt] = __builtin_amdgcn_mfma_f32_16x16x32_bf16(pA, v, oA[nt], 0, 0, 0);
        }
    }

    // ---- merge wave-pair (kv-half) partials via LDS overlay, finalize ----
    float lfA = lsA + __shfl_xor(lsA, 16, 64);
    lfA += __shfl_xor(lfA, 32, 64);
    float lfB = lsB + __shfl_xor(lsB, 16, 64);
    lfB += __shfl_xor(lfB, 32, 64);
    __syncthreads();  // all compute done; K/V/P LDS dead -> reuse
    float* mA = (float*)smem;       // [64][66] f32 tile-A partials
    float* mB = mA + 64 * 66;       // [64][66] f32 tile-B partials
    float* lAr = mB + 64 * 66;      // [64] row sums (tile A, half 1)
    float* lBr = lAr + 64;          // [64] row sums (tile B, half 0)
    if (hv) {
#pragma unroll
        for (int nt = 0; nt < 4; ++nt)
#pragma unroll
            for (int r = 0; r < 4; ++r)
                mA[(wq * 16 + quad * 4 + r) * 66 + nt * 16 + lr] = oA[nt][r];
        if (lane < 16) lAr[wq * 16 + lane] = lfA;
    } else {
#pragma unroll
        for (int nt = 0; nt < 4; ++nt)
#pragma unroll
            for (int r = 0; r < 4; ++r)
                mB[(wq * 16 + quad * 4 + r) * 66 + nt * 16 + lr] = oB[nt][r];
        if (lane < 16) lBr[wq * 16 + lane] = lfB;
    }
    __syncthreads();
    if (!hv) {  // waves 0-3 finalize tile A
        float lff = lfA + lAr[wq * 16 + lr];
#pragma unroll
        for (int r = 0; r < 4; ++r) {
            float inv = 1.0f / __shfl(lff, quad * 4 + r, 64);
            size_t row = (size_t)(b * S_LEN + tA * 64 + wq * 16 + quad * 4 + r) * EMB + h * HD;
#pragma unroll
            for (int nt = 0; nt < 4; ++nt)
                e[row + nt * 16 + lr] =
                    f2bf((oA[nt][r] + mA[(wq * 16 + quad * 4 + r) * 66 + nt * 16 + lr]) * inv);
        }
    } else {  // waves 4-7 finalize tile B
        float lff = lfB + lBr[wq * 16 + lr];
#pragma unroll
        for (int r = 0; r < 4; ++r) {
            float inv = 1.0f / __shfl(lff, quad * 4 + r, 64);
            size_t row = (size_t)(b * S_LEN + tB * 64 + wq * 16 + quad * 4 + r) * EMB + h * HD;
#pragma unroll
            for (int nt = 0; nt < 4; ++nt)
                e[row + nt * 16 + lr] =
                    f2bf((oB[nt][r] + mB[(wq * 16 + quad * 4 + r) * 66 + nt * 16 + lr]) * inv);
        }
    }
}

// ---------------- launcher ----------------
extern "C" void kernel_launch(void* const* d_in, const int* in_sizes, int n_in,
                              void* d_out, int out_size, void* d_ws, size_t ws_size,
                              hipStream_t stream) {
    const float* x = (const float*)d_in[0];
    const float* w_qkv = (const float*)d_in[1];
    const float* w0 = (const float*)d_in[2];
    float* out = (float*)d_out;

    const size_t M = (size_t)BATCH * S_LEN;  // 4096
    u16* xb = (u16*)d_ws;
    u16* wqb = xb + M * EMB;
    u16* w0b = wqb + (size_t)QKV_W * EMB;
    u16* qkvb = w0b + (size_t)EMB * EMB;
    u16* vtb = qkvb + M * QKV_W;
    u16* eb = vtb + (size_t)BATCH * NH * HD * S_LEN;

    cvt_all<<<(XN4 + WQ4 + W04) / 256, 256, 0, stream>>>(x, w_qkv, w0, xb, wqb, w0b);

    // qkv = x @ w_qkv^T; Q columns pre-scaled by CSC
    gemm_bt<u16, 128><<<dim3(QKV_W / 128, M / 128), 256, 0, stream>>>(
        xb, wqb, qkvb, (int)M, QKV_W, EMB, EMB);

    transpose_v<<<dim3(S_LEN / 64, BATCH * NH), 256, 0, stream>>>(qkvb, vtb);

    attn<<<dim3(16, BATCH * NH), 512, 0, stream>>>(qkvb, vtb, eb);

    // out = e @ w0^T (128x64 tiles -> 512 blocks, 2/CU)
    gemm_bt<float, 64><<<dim3(EMB / 64, M / 128), 256, 0, stream>>>(
        eb, w0b, out, (int)M, EMB, EMB, 0);
}